// Round 9
// baseline (124.367 us; speedup 1.0000x reference)
//
#include <hip/hip_runtime.h>
#include <hip/hip_fp16.h>
#include <math.h>

#define NQ 8
#define DK 64
#define NB 8
#define NS 1024
#define RB 16           // rows per block in attn kernel

typedef _Float16 h2v __attribute__((ext_vector_type(2)));

__device__ __forceinline__ float fdot2h(unsigned qu, unsigned ku, float acc) {
#if defined(__has_builtin) && __has_builtin(__builtin_amdgcn_fdot2)
    union { unsigned u; h2v h; } a, b;
    a.u = qu; b.u = ku;
    return __builtin_amdgcn_fdot2(a.h, b.h, acc, false);
#else
    __half2 qh = *(__half2*)&qu, kh = *(__half2*)&ku;
    float2 qf = __half22float2(qh), kf = __half22float2(kh);
    return fmaf(qf.x, kf.x, fmaf(qf.y, kf.y, acc));
#endif
}

// ---------------- prep: values GEMM (blocks 0..2047) + density features ----------------
// qdh/kdh fp16 [tok][n*4 + {d0,d1,re,im}]; factor 2 folded into kdh cross terms.
__global__ __launch_bounds__(256) void prep_kernel(
    const float* __restrict__ x,
    const float* __restrict__ theta_q,
    const float* __restrict__ theta_k,
    const float* __restrict__ Wv,
    const float* __restrict__ bv,
    __half* __restrict__ qdh, __half* __restrict__ kdh,
    float* __restrict__ values) {
    int bid = blockIdx.x;
    int tid = threadIdx.x;
    if (bid < 2048) {
        // values = x @ Wv^T + bv (4 partial chains)
        int t = bid * 4 + (tid >> 6);
        int d = tid & 63;
        const float4* xr = (const float4*)(x + (size_t)t * DK);
        const float4* wr = (const float4*)(Wv + (size_t)d * DK);
        float a0 = bv[d], a1 = 0.f, a2 = 0.f, a3 = 0.f;
#pragma unroll
        for (int j = 0; j < DK / 4; ++j) {
            float4 xv = xr[j], wv = wr[j];
            a0 = fmaf(xv.x, wv.x, a0);
            a1 = fmaf(xv.y, wv.y, a1);
            a2 = fmaf(xv.z, wv.z, a2);
            a3 = fmaf(xv.w, wv.w, a3);
        }
        values[(size_t)t * DK + d] = (a0 + a1) + (a2 + a3);
    } else {
        // per-(side,qubit) theta trig table, computed once per block
        __shared__ float tt[2][NQ][6];   // ct,st,cmpo,smpo,cpmo,spmo
        if (tid < 16) {
            int side = tid >> 3, n = tid & 7;
            const float* thp = side ? theta_k : theta_q;
            float phi = thp[n * 3 + 0], th = thp[n * 3 + 1], om = thp[n * 3 + 2];
            float st, ct; __sincosf(0.5f * th, &st, &ct);
            float smpo, cmpo; __sincosf(0.5f * (phi + om), &smpo, &cmpo);
            float spmo, cpmo; __sincosf(0.5f * (phi - om), &spmo, &cpmo);
            tt[side][n][0] = ct;  tt[side][n][1] = st;
            tt[side][n][2] = cmpo; tt[side][n][3] = smpo;
            tt[side][n][4] = cpmo; tt[side][n][5] = spmo;
        }
        __syncthreads();

        int gid = (bid - 2048) * 256 + tid;   // 0..65535
        int tok = gid >> 3;
        int n = gid & 7;
        float xin = x[(size_t)tok * DK + n];
        float ex = __expf(2.0f * xin);               // fast tanh
        float xn = 1.0f - 2.0f / (ex + 1.0f);
        float s, c;
        __sincosf(xn * 1.57079632679489662f, &s, &c);

#pragma unroll
        for (int side = 0; side < 2; ++side) {
            float ct = tt[side][n][0], st = tt[side][n][1];
            float cmpo = tt[side][n][2], smpo = tt[side][n][3];
            float cpmo = tt[side][n][4], spmo = tt[side][n][5];
            float a = ct * c, b2 = st * s, cc = st * c, d2 = ct * s;
            float a0re =  cmpo * a - cpmo * b2;
            float a0im = -smpo * a - spmo * b2;
            float a1re =  cpmo * cc + cmpo * d2;
            float a1im = -spmo * cc + smpo * d2;
            float d0 = fmaf(a0re, a0re, a0im * a0im);
            float d1 = fmaf(a1re, a1re, a1im * a1im);
            float ur = fmaf(a1re, a0re, a1im * a0im);
            float ui = fmaf(a1im, a0re, -a1re * a0im);
            if (side == 0) {
                __half2* qp = (__half2*)(qdh + (size_t)tok * 32 + n * 4);
                qp[0] = __floats2half2_rn(d0, d1);
                qp[1] = __floats2half2_rn(ur, ui);
            } else {
                __half2* kp = (__half2*)(kdh + (size_t)tok * 32 + n * 4);
                kp[0] = __floats2half2_rn(d0, d1);
                kp[1] = __floats2half2_rn(2.f * ur, 2.f * ui);
            }
        }
    }
}

// ---------------- attn: fused scores -> softmax -> attn + PV ----------------
// 512 blocks x 512 threads (8 waves); block owns 16 rows of one batch.
// Scores: wave w owns token slice [w*128, w*128+128) for ALL 16 rows (q uniform).
__global__ __launch_bounds__(512, 4) void attn_kernel(
    const __half* __restrict__ qdh, const __half* __restrict__ kdh,
    const float* __restrict__ values,
    float* __restrict__ out, float* __restrict__ attn) {
    __shared__ float e_lds[RB][NS];      // 64 KB; reused as [32][8][64] reduce scratch
    __shared__ float red_lds[8][RB];
    __shared__ float inv_lds[RB];

    int tid = threadIdx.x;
    int gr0 = blockIdx.x * RB;           // global row base (= b*NS + s0)
    int b = gr0 >> 10;
    int w = tid >> 6, lane = tid & 63;

    const __half* kfb = kdh + (size_t)b * NS * 32;

    // ---- Phase 1: K slice for this wave (2 tokens per lane), all 16 rows ----
    int t0 = w * 128;
    uint4 ka[4], kb[4];
    {
        const uint4* kp0 = (const uint4*)(kfb + (size_t)(t0 + lane) * 32);
        const uint4* kp1 = (const uint4*)(kfb + (size_t)(t0 + 64 + lane) * 32);
#pragma unroll
        for (int i = 0; i < 4; ++i) { ka[i] = kp0[i]; kb[i] = kp1[i]; }
    }

    float sums[RB];
#pragma unroll
    for (int r = 0; r < RB; ++r) sums[r] = 0.f;

#pragma unroll
    for (int r = 0; r < RB; ++r) {
        const uint4* qp = (const uint4*)(qdh + (size_t)(gr0 + r) * 32);
        uint4 q0 = qp[0], q1 = qp[1], q2 = qp[2], q3 = qp[3];  // wave-uniform
        // token t0+lane
        {
            float m0 = fdot2h(q0.x, ka[0].x, fdot2h(q0.y, ka[0].y, 0.f));
            float m1 = fdot2h(q0.z, ka[0].z, fdot2h(q0.w, ka[0].w, 0.f));
            float m2 = fdot2h(q1.x, ka[1].x, fdot2h(q1.y, ka[1].y, 0.f));
            float m3 = fdot2h(q1.z, ka[1].z, fdot2h(q1.w, ka[1].w, 0.f));
            float m4 = fdot2h(q2.x, ka[2].x, fdot2h(q2.y, ka[2].y, 0.f));
            float m5 = fdot2h(q2.z, ka[2].z, fdot2h(q2.w, ka[2].w, 0.f));
            float m6 = fdot2h(q3.x, ka[3].x, fdot2h(q3.y, ka[3].y, 0.f));
            float m7 = fdot2h(q3.z, ka[3].z, fdot2h(q3.w, ka[3].w, 0.f));
            float core = ((m0 * m1) * (m2 * m3)) * ((m4 * m5) * (m6 * m7));
            float e = __expf(fmaf(core, 0.5f, 0.5f));   // score in [0.5,1]
            e_lds[r][t0 + lane] = e;
            sums[r] += e;
        }
        // token t0+64+lane
        {
            float m0 = fdot2h(q0.x, kb[0].x, fdot2h(q0.y, kb[0].y, 0.f));
            float m1 = fdot2h(q0.z, kb[0].z, fdot2h(q0.w, kb[0].w, 0.f));
            float m2 = fdot2h(q1.x, kb[1].x, fdot2h(q1.y, kb[1].y, 0.f));
            float m3 = fdot2h(q1.z, kb[1].z, fdot2h(q1.w, kb[1].w, 0.f));
            float m4 = fdot2h(q2.x, kb[2].x, fdot2h(q2.y, kb[2].y, 0.f));
            float m5 = fdot2h(q2.z, kb[2].z, fdot2h(q2.w, kb[2].w, 0.f));
            float m6 = fdot2h(q3.x, kb[3].x, fdot2h(q3.y, kb[3].y, 0.f));
            float m7 = fdot2h(q3.z, kb[3].z, fdot2h(q3.w, kb[3].w, 0.f));
            float core = ((m0 * m1) * (m2 * m3)) * ((m4 * m5) * (m6 * m7));
            float e = __expf(fmaf(core, 0.5f, 0.5f));
            e_lds[r][t0 + 64 + lane] = e;
            sums[r] += e;
        }
    }

    // per-wave partial row sums -> cross-wave combine
#pragma unroll
    for (int r = 0; r < RB; ++r) {
#pragma unroll
        for (int m = 1; m < 64; m <<= 1) sums[r] += __shfl_xor(sums[r], m, 64);
    }
    if (lane == 0) {
#pragma unroll
        for (int r = 0; r < RB; ++r) red_lds[w][r] = sums[r];
    }
    __syncthreads();
    if (tid < RB) {
        float s = 0.f;
#pragma unroll
        for (int g = 0; g < 8; ++g) s += red_lds[g][tid];
        inv_lds[tid] = 1.f / s;
    }
    __syncthreads();

    // ---- Phase 2: write normalized attn (coalesced float2) ----
    float* ab = attn + (size_t)gr0 * NS;
#pragma unroll
    for (int r = 0; r < RB; ++r) {
        float iv = inv_lds[r];
        float2 e2 = *(const float2*)&e_lds[r][tid * 2];
        *(float2*)&ab[(size_t)r * NS + tid * 2] = make_float2(e2.x * iv, e2.y * iv);
    }

    // ---- Phase 3: PV. thread (tg 0..31, dg 0..15): t = jj*128 + tg*4 ----
    int tg = tid >> 4, dg = tid & 15;
    const float* vb = values + (size_t)b * NS * DK;
    float acc[RB][4];
#pragma unroll
    for (int r = 0; r < RB; ++r) { acc[r][0] = acc[r][1] = acc[r][2] = acc[r][3] = 0.f; }

    for (int jj = 0; jj < 8; ++jj) {
        int t = jj * 128 + tg * 4;
        const float* vp = vb + (size_t)t * DK + dg * 4;
        float4 v0 = *(const float4*)(vp);
        float4 v1 = *(const float4*)(vp + DK);
        float4 v2 = *(const float4*)(vp + 2 * DK);
        float4 v3 = *(const float4*)(vp + 3 * DK);
#pragma unroll
        for (int r = 0; r < RB; ++r) {
            float4 e4 = *(const float4*)&e_lds[r][t];
            acc[r][0] = fmaf(e4.x, v0.x, fmaf(e4.y, v1.x, fmaf(e4.z, v2.x, fmaf(e4.w, v3.x, acc[r][0]))));
            acc[r][1] = fmaf(e4.x, v0.y, fmaf(e4.y, v1.y, fmaf(e4.z, v2.y, fmaf(e4.w, v3.y, acc[r][1]))));
            acc[r][2] = fmaf(e4.x, v0.z, fmaf(e4.y, v1.z, fmaf(e4.z, v2.z, fmaf(e4.w, v3.z, acc[r][2]))));
            acc[r][3] = fmaf(e4.x, v0.w, fmaf(e4.y, v1.w, fmaf(e4.z, v2.w, fmaf(e4.w, v3.w, acc[r][3]))));
        }
    }

    // ---- out reduce: reuse e_lds as [32 tg][8 r][64 d] scratch, two halves ----
    __syncthreads();                     // all PV reads of e_lds complete
    float* red = &e_lds[0][0];
#pragma unroll
    for (int h = 0; h < 2; ++h) {
        if (h) __syncthreads();          // previous half's reduce reads done
#pragma unroll
        for (int r = 0; r < 8; ++r) {
            *(float4*)&red[((size_t)tg * 8 + r) * 64 + dg * 4] =
                make_float4(acc[h * 8 + r][0], acc[h * 8 + r][1],
                            acc[h * 8 + r][2], acc[h * 8 + r][3]);
        }
        __syncthreads();
        int rr = tid >> 6;               // 0..7
        int d = tid & 63;
        float o = 0.f;
#pragma unroll
        for (int g = 0; g < 32; ++g) o += red[((size_t)g * 8 + rr) * 64 + d];
        out[((size_t)(gr0 + h * 8 + rr)) * DK + d] = o * inv_lds[h * 8 + rr];
    }
}

extern "C" void kernel_launch(void* const* d_in, const int* in_sizes, int n_in,
                              void* d_out, int out_size, void* d_ws, size_t ws_size,
                              hipStream_t stream) {
    const float* x       = (const float*)d_in[0];
    const float* theta_q = (const float*)d_in[1];
    const float* theta_k = (const float*)d_in[2];
    const float* W_v     = (const float*)d_in[3];
    const float* b_v     = (const float*)d_in[4];

    float* out  = (float*)d_out;                        // [8,1024,64]
    float* attn = (float*)d_out + (size_t)NB * NS * DK; // [8,1024,1024]

    __half* qdh    = (__half*)d_ws;                          // 512 KB fp16
    __half* kdh    = qdh + (size_t)NB * NS * 32;             // 512 KB fp16
    float*  values = (float*)(kdh + (size_t)NB * NS * 32);   // 2 MB fp32

    prep_kernel<<<2048 + NB * NS * NQ / 256, 256, 0, stream>>>(
        x, theta_q, theta_k, W_v, b_v, qdh, kdh, values);
    attn_kernel<<<NB * NS / RB, 512, 0, stream>>>(qdh, kdh, values, out, attn);
}

// Round 10
// 54.142 us; speedup vs baseline: 2.2971x; 2.2971x over previous
//
#include <hip/hip_runtime.h>
#include <hip/hip_fp16.h>
#include <math.h>

#define NQ 8
#define DK 64
#define NB 8
#define NS 1024
#define RB 8            // rows per block in attn kernel

typedef _Float16 h2v __attribute__((ext_vector_type(2)));

__device__ __forceinline__ float fdot2h(unsigned qu, unsigned ku, float acc) {
#if defined(__has_builtin) && __has_builtin(__builtin_amdgcn_fdot2)
    union { unsigned u; h2v h; } a, b;
    a.u = qu; b.u = ku;
    return __builtin_amdgcn_fdot2(a.h, b.h, acc, false);
#else
    __half2 qh = *(__half2*)&qu, kh = *(__half2*)&ku;
    float2 qf = __half22float2(qh), kf = __half22float2(kh);
    return fmaf(qf.x, kf.x, fmaf(qf.y, kf.y, acc));
#endif
}

// ---------------- prep: values GEMM (blocks 0..2047) + density features ----------------
// qdh/kdh fp16 [tok][n*4 + {d0,d1,re,im}]; factor 2 folded into kdh cross terms.
__global__ __launch_bounds__(256) void prep_kernel(
    const float* __restrict__ x,
    const float* __restrict__ theta_q,
    const float* __restrict__ theta_k,
    const float* __restrict__ Wv,
    const float* __restrict__ bv,
    __half* __restrict__ qdh, __half* __restrict__ kdh,
    float* __restrict__ values) {
    int bid = blockIdx.x;
    int tid = threadIdx.x;
    if (bid < 2048) {
        // values = x @ Wv^T + bv (4 partial chains)
        int t = bid * 4 + (tid >> 6);
        int d = tid & 63;
        const float4* xr = (const float4*)(x + (size_t)t * DK);
        const float4* wr = (const float4*)(Wv + (size_t)d * DK);
        float a0 = bv[d], a1 = 0.f, a2 = 0.f, a3 = 0.f;
#pragma unroll
        for (int j = 0; j < DK / 4; ++j) {
            float4 xv = xr[j], wv = wr[j];
            a0 = fmaf(xv.x, wv.x, a0);
            a1 = fmaf(xv.y, wv.y, a1);
            a2 = fmaf(xv.z, wv.z, a2);
            a3 = fmaf(xv.w, wv.w, a3);
        }
        values[(size_t)t * DK + d] = (a0 + a1) + (a2 + a3);
    } else {
        // per-(side,qubit) theta trig table, computed once per block
        __shared__ float tt[2][NQ][6];   // ct,st,cmpo,smpo,cpmo,spmo
        if (tid < 16) {
            int side = tid >> 3, n = tid & 7;
            const float* thp = side ? theta_k : theta_q;
            float phi = thp[n * 3 + 0], th = thp[n * 3 + 1], om = thp[n * 3 + 2];
            float st, ct; __sincosf(0.5f * th, &st, &ct);
            float smpo, cmpo; __sincosf(0.5f * (phi + om), &smpo, &cmpo);
            float spmo, cpmo; __sincosf(0.5f * (phi - om), &spmo, &cpmo);
            tt[side][n][0] = ct;  tt[side][n][1] = st;
            tt[side][n][2] = cmpo; tt[side][n][3] = smpo;
            tt[side][n][4] = cpmo; tt[side][n][5] = spmo;
        }
        __syncthreads();

        int gid = (bid - 2048) * 256 + tid;   // 0..65535
        int tok = gid >> 3;
        int n = gid & 7;
        float xin = x[(size_t)tok * DK + n];
        float ex = __expf(2.0f * xin);               // fast tanh
        float xn = 1.0f - 2.0f / (ex + 1.0f);
        float s, c;
        __sincosf(xn * 1.57079632679489662f, &s, &c);

#pragma unroll
        for (int side = 0; side < 2; ++side) {
            float ct = tt[side][n][0], st = tt[side][n][1];
            float cmpo = tt[side][n][2], smpo = tt[side][n][3];
            float cpmo = tt[side][n][4], spmo = tt[side][n][5];
            float a = ct * c, b2 = st * s, cc = st * c, d2 = ct * s;
            float a0re =  cmpo * a - cpmo * b2;
            float a0im = -smpo * a - spmo * b2;
            float a1re =  cpmo * cc + cmpo * d2;
            float a1im = -spmo * cc + smpo * d2;
            float d0 = fmaf(a0re, a0re, a0im * a0im);
            float d1 = fmaf(a1re, a1re, a1im * a1im);
            float ur = fmaf(a1re, a0re, a1im * a0im);
            float ui = fmaf(a1im, a0re, -a1re * a0im);
            if (side == 0) {
                __half2* qp = (__half2*)(qdh + (size_t)tok * 32 + n * 4);
                qp[0] = __floats2half2_rn(d0, d1);
                qp[1] = __floats2half2_rn(ur, ui);
            } else {
                __half2* kp = (__half2*)(kdh + (size_t)tok * 32 + n * 4);
                kp[0] = __floats2half2_rn(d0, d1);
                kp[1] = __floats2half2_rn(2.f * ur, 2.f * ui);
            }
        }
    }
}

// ---------------- attn: fused scores -> softmax -> attn + PV ----------------
// 1024 blocks x 256 threads (4 waves); block owns 8 rows of one batch.
// Phase 1: wave w owns token slice [256w, 256w+256) held in VGPRs, for ALL 8 rows.
__global__ __launch_bounds__(256, 4) void attn_kernel(
    const __half* __restrict__ qdh, const __half* __restrict__ kdh,
    const float* __restrict__ values,
    float* __restrict__ out, float* __restrict__ attn) {
    __shared__ float e_lds[RB][NS];   // 32 KB; reused as [16][4][64] reduce scratch
    __shared__ float red_lds[4][RB];
    __shared__ float inv_lds[RB];

    int tid = threadIdx.x;
    int gr0 = blockIdx.x * RB;            // global row base (= b*NS + s0)
    int b = gr0 >> 10;
    int w = tid >> 6, lane = tid & 63;

    const __half* kfb = kdh + (size_t)b * NS * 32;

    // ---- Phase 1: load wave's K slice (4 tokens per lane, 64 VGPRs) ----
    int t0 = w * 256;
    uint4 kv[4][4];
#pragma unroll
    for (int j = 0; j < 4; ++j) {
        const uint4* kp = (const uint4*)(kfb + (size_t)(t0 + j * 64 + lane) * 32);
        kv[j][0] = kp[0]; kv[j][1] = kp[1]; kv[j][2] = kp[2]; kv[j][3] = kp[3];
    }

    float sums[RB];
#pragma unroll
    for (int r = 0; r < RB; ++r) sums[r] = 0.f;

#pragma unroll
    for (int r = 0; r < RB; ++r) {
        const unsigned* qp = (const unsigned*)(qdh + (size_t)(gr0 + r) * 32);
        unsigned sq[16];
#pragma unroll
        for (int i = 0; i < 16; ++i) sq[i] = __builtin_amdgcn_readfirstlane(qp[i]);
#pragma unroll
        for (int j = 0; j < 4; ++j) {
            float m0 = fdot2h(sq[ 0], kv[j][0].x, fdot2h(sq[ 1], kv[j][0].y, 0.f));
            float m1 = fdot2h(sq[ 2], kv[j][0].z, fdot2h(sq[ 3], kv[j][0].w, 0.f));
            float m2 = fdot2h(sq[ 4], kv[j][1].x, fdot2h(sq[ 5], kv[j][1].y, 0.f));
            float m3 = fdot2h(sq[ 6], kv[j][1].z, fdot2h(sq[ 7], kv[j][1].w, 0.f));
            float m4 = fdot2h(sq[ 8], kv[j][2].x, fdot2h(sq[ 9], kv[j][2].y, 0.f));
            float m5 = fdot2h(sq[10], kv[j][2].z, fdot2h(sq[11], kv[j][2].w, 0.f));
            float m6 = fdot2h(sq[12], kv[j][3].x, fdot2h(sq[13], kv[j][3].y, 0.f));
            float m7 = fdot2h(sq[14], kv[j][3].z, fdot2h(sq[15], kv[j][3].w, 0.f));
            float core = ((m0 * m1) * (m2 * m3)) * ((m4 * m5) * (m6 * m7));
            float e = __expf(fmaf(core, 0.5f, 0.5f));   // score in [0.5,1] -> no max
            e_lds[r][t0 + j * 64 + lane] = e;
            sums[r] += e;
        }
    }

    // per-wave partial row sums -> cross-wave combine
#pragma unroll
    for (int r = 0; r < RB; ++r) {
#pragma unroll
        for (int m = 1; m < 64; m <<= 1) sums[r] += __shfl_xor(sums[r], m, 64);
    }
    if (lane == 0) {
#pragma unroll
        for (int r = 0; r < RB; ++r) red_lds[w][r] = sums[r];
    }
    __syncthreads();
    if (tid < RB)
        inv_lds[tid] = 1.f / (red_lds[0][tid] + red_lds[1][tid] + red_lds[2][tid] + red_lds[3][tid]);
    __syncthreads();

    // ---- Phase 2: write normalized attn (coalesced float4) ----
    float* ab = attn + (size_t)gr0 * NS;
#pragma unroll
    for (int r = 0; r < RB; ++r) {
        float4 e4 = *(const float4*)&e_lds[r][tid * 4];
        float iv = inv_lds[r];
        *(float4*)&ab[(size_t)r * NS + tid * 4] =
            make_float4(e4.x * iv, e4.y * iv, e4.z * iv, e4.w * iv);
    }

    // ---- Phase 3: PV on unnormalized e; thread (tg 0..15, dg 0..15) ----
    int tg = tid >> 4, dg = tid & 15;
    const float* vb = values + (size_t)b * NS * DK;
    float acc[RB][4];
#pragma unroll
    for (int r = 0; r < RB; ++r) { acc[r][0] = acc[r][1] = acc[r][2] = acc[r][3] = 0.f; }

    for (int jj = 0; jj < 16; ++jj) {
        int t = jj * 64 + tg * 4;
        const float* vp = vb + (size_t)t * DK + dg * 4;
        float4 v0 = *(const float4*)(vp);
        float4 v1 = *(const float4*)(vp + DK);
        float4 v2 = *(const float4*)(vp + 2 * DK);
        float4 v3 = *(const float4*)(vp + 3 * DK);
#pragma unroll
        for (int r = 0; r < RB; ++r) {
            float4 e4 = *(const float4*)&e_lds[r][t];
            acc[r][0] = fmaf(e4.x, v0.x, fmaf(e4.y, v1.x, fmaf(e4.z, v2.x, fmaf(e4.w, v3.x, acc[r][0]))));
            acc[r][1] = fmaf(e4.x, v0.y, fmaf(e4.y, v1.y, fmaf(e4.z, v2.y, fmaf(e4.w, v3.y, acc[r][1]))));
            acc[r][2] = fmaf(e4.x, v0.z, fmaf(e4.y, v1.z, fmaf(e4.z, v2.z, fmaf(e4.w, v3.z, acc[r][2]))));
            acc[r][3] = fmaf(e4.x, v0.w, fmaf(e4.y, v1.w, fmaf(e4.z, v2.w, fmaf(e4.w, v3.w, acc[r][3]))));
        }
    }

    // ---- out reduce: reuse e_lds as [16][4][64] fp32 scratch, two halves ----
    float* red = &e_lds[0][0];
#pragma unroll
    for (int h = 0; h < 2; ++h) {
        __syncthreads();    // previous readers of e_lds/red done
#pragma unroll
        for (int r = 0; r < 4; ++r) {
            *(float4*)&red[((size_t)tg * 4 + r) * 64 + dg * 4] =
                make_float4(acc[h * 4 + r][0], acc[h * 4 + r][1],
                            acc[h * 4 + r][2], acc[h * 4 + r][3]);
        }
        __syncthreads();
        int r2 = tid >> 6, d = tid & 63;
        float o = 0.f;
#pragma unroll
        for (int g = 0; g < 16; ++g) o += red[((size_t)g * 4 + r2) * 64 + d];
        out[((size_t)(gr0 + h * 4 + r2)) * DK + d] = o * inv_lds[h * 4 + r2];
    }
}

extern "C" void kernel_launch(void* const* d_in, const int* in_sizes, int n_in,
                              void* d_out, int out_size, void* d_ws, size_t ws_size,
                              hipStream_t stream) {
    const float* x       = (const float*)d_in[0];
    const float* theta_q = (const float*)d_in[1];
    const float* theta_k = (const float*)d_in[2];
    const float* W_v     = (const float*)d_in[3];
    const float* b_v     = (const float*)d_in[4];

    float* out  = (float*)d_out;                        // [8,1024,64]
    float* attn = (float*)d_out + (size_t)NB * NS * DK; // [8,1024,1024]

    __half* qdh    = (__half*)d_ws;                          // 512 KB fp16
    __half* kdh    = qdh + (size_t)NB * NS * 32;             // 512 KB fp16
    float*  values = (float*)(kdh + (size_t)NB * NS * 32);   // 2 MB fp32

    prep_kernel<<<2048 + NB * NS * NQ / 256, 256, 0, stream>>>(
        x, theta_q, theta_k, W_v, b_v, qdh, kdh, values);
    attn_kernel<<<NB * NS / RB, 256, 0, stream>>>(qdh, kdh, values, out, attn);
}